// Round 3
// baseline (572.486 us; speedup 1.0000x reference)
//
#include <hip/hip_runtime.h>

// Problem constants
#define BATCH 16
#define NROW  10647
#define ROWF  85          // 4 box + 1 obj + 80 cls
#define NCLS  80
#define KTOP  2048
#define MPAD  16384       // next pow2 >= NROW
#define SCORE_THR 0.5f
#define IOU_THR   0.5f

typedef unsigned long long u64;
typedef unsigned int u32;

__device__ __forceinline__ u32 enc_f32(float f) {
    u32 u = __float_as_uint(f);
    return (u & 0x80000000u) ? ~u : (u | 0x80000000u);
}
__device__ __forceinline__ float dec_f32(u32 e) {
    u32 u = (e & 0x80000000u) ? (e & 0x7FFFFFFFu) : ~e;
    return __uint_as_float(u);
}
__device__ __forceinline__ float bcast(float v, int ii) {
    return __uint_as_float(__builtin_amdgcn_readlane(__float_as_uint(v), ii));
}
__device__ __forceinline__ u64 rl64(u64 v, int l) {
    u32 lo = __builtin_amdgcn_readlane((u32)(v & 0xFFFFFFFFull), l);
    u32 hi = __builtin_amdgcn_readlane((u32)(v >> 32), l);
    return ((u64)hi << 32) | (u64)lo;
}

// ---------------------------------------------------------------------------
// Kernel 1: scores -> sortable u64 keys.  key = enc(score)<<32 | (~idx)
// grid: (128 tiles, BATCH), block: 256.  Rows >= NROW emit key=0.
// ---------------------------------------------------------------------------
__global__ void score_kernel(const float* __restrict__ yp, u64* __restrict__ keys) {
    __shared__ float tile[128 * ROWF];   // 43520 B
    const int tileIdx = blockIdx.x;
    const int b = blockIdx.y;
    const int tid = threadIdx.x;
    const int batch_lim = NROW * ROWF;
    const int tile_base = tileIdx * 128 * ROWF;

    if (tile_base < batch_lim) {
        const float* src = yp + (long long)b * batch_lim;
        for (int e = tid; e < 128 * ROWF; e += 256) {
            float v = 0.f;
            if (tile_base + e < batch_lim) v = src[tile_base + e];
            tile[e] = v;
        }
    }
    __syncthreads();

    if (tid < 128) {
        int gr = tileIdx * 128 + tid;          // < MPAD always
        u64 key = 0ULL;
        if (gr < NROW) {
            const float* r = &tile[tid * ROWF];
            float obj = r[4];
            float m = r[5];
            #pragma unroll
            for (int c = 1; c < NCLS; ++c) m = fmaxf(m, r[5 + c]);
            float s = obj * m;
            key = ((u64)enc_f32(s) << 32) | (u64)(0xFFFFFFFFu - (u32)gr);
        }
        keys[(long long)b * MPAD + gr] = key;
    }
}

// ---------------------------------------------------------------------------
// Kernel 2a: sort each 2048-chunk descending (chunks 0..5 cover all real rows;
// chunks 6,7 are all-zero keys and are skipped). grid (6, BATCH), block 256.
// ---------------------------------------------------------------------------
__global__ void chunk_sort_kernel(u64* __restrict__ keys) {
    __shared__ u64 sm[2048];   // 16 KiB
    const int b = blockIdx.y, c = blockIdx.x, tid = threadIdx.x;
    u64* base = keys + (long long)b * MPAD + c * 2048;
    for (int t = tid; t < 2048; t += 256) sm[t] = base[t];
    __syncthreads();
    for (int k = 2; k <= 2048; k <<= 1) {
        for (int j = k >> 1; j > 0; j >>= 1) {
            for (int t = tid; t < 2048; t += 256) {
                int ixj = t ^ j;
                if (ixj > t) {
                    u64 a = sm[t], cc = sm[ixj];
                    bool up = ((t & k) == 0);
                    if (up ? (a < cc) : (a > cc)) { sm[t] = cc; sm[ixj] = a; }
                }
            }
            __syncthreads();
        }
    }
    for (int t = tid; t < 2048; t += 256) base[t] = sm[t];
}

// Half-cleaner top-2048 of two descending 2048-seqs, then bitonic cleanup.
__device__ __forceinline__ void merge_top2048(const u64* __restrict__ a,
                                              const u64* __restrict__ bseq,
                                              u64* sm, int tid) {
    for (int t = tid; t < 2048; t += 256) {
        u64 va = a[t], vb = bseq[2047 - t];
        sm[t] = va > vb ? va : vb;
    }
    __syncthreads();
    for (int j = 1024; j > 0; j >>= 1) {
        for (int t = tid; t < 2048; t += 256) {
            int ixj = t ^ j;
            if (ixj > t) {
                u64 x = sm[t], y = sm[ixj];
                if (x < y) { sm[t] = y; sm[ixj] = x; }
            }
        }
        __syncthreads();
    }
}

// Kernel 2b: round 1 — (0,1)->B0, (2,3)->B1, (4,5)->B2. grid (3, BATCH).
__global__ void merge_r1_kernel(const u64* __restrict__ keysA, u64* __restrict__ keysB) {
    __shared__ u64 sm[2048];
    const int b = blockIdx.y, c = blockIdx.x, tid = threadIdx.x;
    const u64* a = keysA + (long long)b * MPAD + c * 4096;
    merge_top2048(a, a + 2048, sm, tid);
    u64* d = keysB + (long long)b * MPAD + c * 2048;
    for (int t = tid; t < 2048; t += 256) d[t] = sm[t];
}

// Kernel 2c: round 2 — (B0,B1)->A0. grid (BATCH).
__global__ void merge_r2_kernel(const u64* __restrict__ keysB, u64* __restrict__ keysA) {
    __shared__ u64 sm[2048];
    const int b = blockIdx.x, tid = threadIdx.x;
    const u64* a = keysB + (long long)b * MPAD;
    merge_top2048(a, a + 2048, sm, tid);
    u64* d = keysA + (long long)b * MPAD;
    for (int t = tid; t < 2048; t += 256) d[t] = sm[t];
}

// Kernel 2d: round 3 — (A0,B2)->final top-2048, fused gather of corners/area.
__global__ void merge_r3_gather_kernel(const u64* __restrict__ keysA,
                                       const u64* __restrict__ keysB,
                                       const float* __restrict__ yp,
                                       float* __restrict__ sx1, float* __restrict__ sy1,
                                       float* __restrict__ sx2, float* __restrict__ sy2,
                                       float* __restrict__ sar, float* __restrict__ ssc) {
    __shared__ u64 sm[2048];
    const int b = blockIdx.x, tid = threadIdx.x;
    merge_top2048(keysA + (long long)b * MPAD, keysB + (long long)b * MPAD + 4096, sm, tid);

    for (int t = tid; t < KTOP; t += 256) {
        u64 key = sm[t];
        float s = dec_f32((u32)(key >> 32));
        u32 idx = 0xFFFFFFFFu - (u32)(key & 0xFFFFFFFFu);
        const float* r = yp + (long long)b * NROW * ROWF + (long long)idx * ROWF;
        float x = r[0], y = r[1], w = r[2], h = r[3];
        float hx = w * 0.5f, hy = h * 0.5f;
        float a1 = x - hx, b1 = y - hy, a2 = x + hx, b2 = y + hy;
        int o = b * KTOP + t;
        sx1[o] = a1; sy1[o] = b1; sx2[o] = a2; sy2[o] = b2;
        sar[o] = fmaxf(a2 - a1, 0.f) * fmaxf(b2 - b1, 0.f);
        ssc[o] = s;
    }
}

// ---------------------------------------------------------------------------
// Kernel 3: pairwise suppression bitmask, 64x64 wave tiles, upper triangle
// only (cb >= rb).  grid (132, BATCH), block 256 (4 waves).
// ---------------------------------------------------------------------------
__global__ void mask_kernel(const float* __restrict__ sx1, const float* __restrict__ sy1,
                            const float* __restrict__ sx2, const float* __restrict__ sy2,
                            const float* __restrict__ sar, u64* __restrict__ mask) {
    const int b = blockIdx.y;
    const int t = blockIdx.x * 4 + (threadIdx.x >> 6);   // 0..527
    const int lane = threadIdx.x & 63;

    // decode upper-triangle tile t -> (rb, cb), cb >= rb
    int rb = (int)((65.0f - sqrtf(4225.0f - 8.0f * (float)t)) * 0.5f);
    while (rb * (65 - rb) / 2 > t) --rb;
    while ((rb + 1) * (64 - rb) / 2 <= t) ++rb;
    const int cb = rb + t - rb * (65 - rb) / 2;

    const int oi = b * KTOP + rb * 64 + lane;
    const int oj = b * KTOP + cb * 64 + lane;
    const float rx1 = sx1[oi], ry1 = sy1[oi], rx2 = sx2[oi], ry2 = sy2[oi], ra = sar[oi];
    const float cx1 = sx1[oj], cy1 = sy1[oj], cx2 = sx2[oj], cy2 = sy2[oj], ca = sar[oj];
    const bool diag = (rb == cb);

    u64 myword = 0ULL;
    for (int ii = 0; ii < 64; ++ii) {
        float ax1 = bcast(rx1, ii), ay1 = bcast(ry1, ii);
        float ax2 = bcast(rx2, ii), ay2 = bcast(ry2, ii);
        float aa  = bcast(ra,  ii);
        float ix1 = fmaxf(ax1, cx1);
        float iy1 = fmaxf(ay1, cy1);
        float ix2 = fminf(ax2, cx2);
        float iy2 = fminf(ay2, cy2);
        float inter = fmaxf(ix2 - ix1, 0.f) * fmaxf(iy2 - iy1, 0.f);
        float uni = aa + ca - inter;
        float iou = inter / fmaxf(uni, 1e-9f);
        bool cond = (iou > IOU_THR) && (!diag || (lane > ii));
        u64 bal = __ballot(cond);
        if (lane == ii) myword = bal;
    }
    mask[(long long)(b * KTOP + rb * 64 + lane) * 32 + cb] = myword;
}

// ---------------------------------------------------------------------------
// Kernel 4: greedy reduce.  Wave 0 per batch: serial chain kept in SGPRs with
// per-block register-resident diagonal words (readlane broadcast, no memory on
// the chain); cross-block suppression via parallel pipelined L2 OR-reduction.
// Then all 4 waves do the masked output write.  grid: BATCH, block: 256.
// ---------------------------------------------------------------------------
__global__ void nms_out_kernel(const float* __restrict__ sx1, const float* __restrict__ sy1,
                               const float* __restrict__ sx2, const float* __restrict__ sy2,
                               const float* __restrict__ ssc,
                               const u64* __restrict__ mask, float* __restrict__ out) {
    __shared__ u64 keepw[32];
    const int b = blockIdx.x;
    const int tid = threadIdx.x;
    const int lane = tid & 63;
    const int wave = tid >> 6;

    if (wave == 0) {
        // init: lanes 0..31 hold keep words = valid bits (score > thr)
        u64 myw = 0ULL;
        for (int c = 0; c < 32; ++c) {
            float s = ssc[b * KTOP + c * 64 + lane];
            u64 bal = __ballot(s > SCORE_THR);
            if (lane == c) myw = bal;
        }

        const u64* mb = mask + (long long)(b * KTOP) * 32;
        const int jb = lane & 31;
        const int half = lane >> 5;

        u64 dia = mb[(0 * 64 + lane) * 32 + 0];      // row lane's diagonal word, block 0
        for (int w = 0; w < 32; ++w) {
            u64 dia_next = (w < 31) ? mb[((w + 1) * 64 + lane) * 32 + (w + 1)] : 0ULL;

            // current keep word for this block, hoisted to SGPRs
            u64 cur_v = __shfl(myw, w);
            u64 cur = ((u64)(u32)__builtin_amdgcn_readfirstlane((u32)(cur_v >> 32)) << 32)
                    | (u64)(u32)__builtin_amdgcn_readfirstlane((u32)cur_v);

            // serial greedy within block: chain is SALU-only
            #pragma unroll
            for (int ii = 0; ii < 64; ++ii) {
                u64 m = ((cur >> ii) & 1ULL) ? rl64(dia, ii) : 0ULL;
                cur &= ~m;
            }

            // parallel suppression of future words: supp[jb] = OR over kept ii
            // lane (jb, half) covers rows ii in [half*32, half*32+32)
            u64 supp = 0ULL;
            #pragma unroll
            for (int s = 0; s < 32; ++s) {
                int ii = half * 32 + s;
                u64 row = mb[((w * 64 + ii) * 32) + jb];       // pipelined, independent
                supp |= (((cur >> ii) & 1ULL) ? row : 0ULL);
            }
            supp |= __shfl_xor(supp, 32);

            if (lane == w) myw = cur;
            else if (lane < 32 && lane > w) myw &= ~supp;     // jb<w words are garbage: never applied

            dia = dia_next;
        }
        if (lane < 32) keepw[lane] = myw;
    }
    __syncthreads();

    for (int t = tid; t < KTOP; t += 256) {
        int o = b * KTOP + t;
        float f = ((keepw[t >> 6] >> (t & 63)) & 1ULL) ? 1.0f : 0.0f;
        float* op = out + (long long)o * 5;
        op[0] = sx1[o] * f;
        op[1] = sy1[o] * f;
        op[2] = sx2[o] * f;
        op[3] = sy2[o] * f;
        op[4] = ssc[o] * f;
    }
}

// ---------------------------------------------------------------------------
extern "C" void kernel_launch(void* const* d_in, const int* in_sizes, int n_in,
                              void* d_out, int out_size, void* d_ws, size_t ws_size,
                              hipStream_t stream) {
    const float* yp = (const float*)d_in[0];
    float* out = (float*)d_out;
    char* ws = (char*)d_ws;

    // Workspace layout (aliasing is safe by kernel ordering):
    //   [0, 2MiB)   keysA          (dead after merge_r3)
    //   [2, 4MiB)   keysB          (dead after merge_r3)
    //   [0, 8MiB)   mask           (written by mask_kernel, after keys die)
    //   [8MiB, +768KiB) SoA arrays (live to the end)
    const size_t KEYS_BYTES = (size_t)BATCH * MPAD * sizeof(u64);        // 2 MiB
    const size_t MASK_BYTES = (size_t)BATCH * KTOP * 32 * sizeof(u64);   // 8 MiB
    u64* keysA = (u64*)ws;
    u64* keysB = (u64*)(ws + KEYS_BYTES);
    u64* mask  = (u64*)ws;
    float* soa = (float*)(ws + MASK_BYTES);
    const int SA = BATCH * KTOP;
    float* sx1 = soa + 0 * SA;
    float* sy1 = soa + 1 * SA;
    float* sx2 = soa + 2 * SA;
    float* sy2 = soa + 3 * SA;
    float* sar = soa + 4 * SA;
    float* ssc = soa + 5 * SA;

    score_kernel<<<dim3(128, BATCH), 256, 0, stream>>>(yp, keysA);
    chunk_sort_kernel<<<dim3(6, BATCH), 256, 0, stream>>>(keysA);
    merge_r1_kernel<<<dim3(3, BATCH), 256, 0, stream>>>(keysA, keysB);
    merge_r2_kernel<<<BATCH, 256, 0, stream>>>(keysB, keysA);
    merge_r3_gather_kernel<<<BATCH, 256, 0, stream>>>(keysA, keysB, yp,
                                                      sx1, sy1, sx2, sy2, sar, ssc);
    mask_kernel<<<dim3(132, BATCH), 256, 0, stream>>>(sx1, sy1, sx2, sy2, sar, mask);
    nms_out_kernel<<<BATCH, 256, 0, stream>>>(sx1, sy1, sx2, sy2, ssc, mask, out);
}

// Round 4
// 293.682 us; speedup vs baseline: 1.9493x; 1.9493x over previous
//
#include <hip/hip_runtime.h>

// Problem constants
#define BATCH 16
#define NROW  10647
#define ROWF  85          // 4 box + 1 obj + 80 cls
#define NCLS  80
#define KTOP  2048
#define MPAD  16384       // next pow2 >= NROW
#define SCORE_THR 0.5f
#define IOU_THR   0.5f

typedef unsigned long long u64;
typedef unsigned int u32;

__device__ __forceinline__ u32 enc_f32(float f) {
    u32 u = __float_as_uint(f);
    return (u & 0x80000000u) ? ~u : (u | 0x80000000u);
}
__device__ __forceinline__ float dec_f32(u32 e) {
    u32 u = (e & 0x80000000u) ? (e & 0x7FFFFFFFu) : ~e;
    return __uint_as_float(u);
}
__device__ __forceinline__ float bcast(float v, int ii) {
    return __uint_as_float(__builtin_amdgcn_readlane(__float_as_uint(v), ii));
}
__device__ __forceinline__ u64 rl64(u64 v, int l) {
    u32 lo = __builtin_amdgcn_readlane((u32)(v & 0xFFFFFFFFull), l);
    u32 hi = __builtin_amdgcn_readlane((u32)(v >> 32), l);
    return ((u64)hi << 32) | (u64)lo;
}

// ---------------------------------------------------------------------------
// Kernel 1: scores -> sortable u64 keys.  key = enc(score)<<32 | (~idx)
// grid: (128 tiles, BATCH), block: 256.  Rows >= NROW emit key=0.
// ---------------------------------------------------------------------------
__global__ void score_kernel(const float* __restrict__ yp, u64* __restrict__ keys) {
    __shared__ float tile[128 * ROWF];   // 43520 B
    const int tileIdx = blockIdx.x;
    const int b = blockIdx.y;
    const int tid = threadIdx.x;
    const int batch_lim = NROW * ROWF;
    const int tile_base = tileIdx * 128 * ROWF;

    if (tile_base < batch_lim) {
        const float* src = yp + (long long)b * batch_lim;
        for (int e = tid; e < 128 * ROWF; e += 256) {
            float v = 0.f;
            if (tile_base + e < batch_lim) v = src[tile_base + e];
            tile[e] = v;
        }
    }
    __syncthreads();

    if (tid < 128) {
        int gr = tileIdx * 128 + tid;          // < MPAD always
        u64 key = 0ULL;
        if (gr < NROW) {
            const float* r = &tile[tid * ROWF];
            float obj = r[4];
            float m = r[5];
            #pragma unroll
            for (int c = 1; c < NCLS; ++c) m = fmaxf(m, r[5 + c]);
            float s = obj * m;
            key = ((u64)enc_f32(s) << 32) | (u64)(0xFFFFFFFFu - (u32)gr);
        }
        keys[(long long)b * MPAD + gr] = key;
    }
}

// ---------------------------------------------------------------------------
// Kernel 2a: sort each 2048-chunk descending (chunks 0..5 cover all real rows;
// chunks 6,7 are all-zero keys and are skipped). grid (6, BATCH), block 256.
// ---------------------------------------------------------------------------
__global__ void chunk_sort_kernel(u64* __restrict__ keys) {
    __shared__ u64 sm[2048];   // 16 KiB
    const int b = blockIdx.y, c = blockIdx.x, tid = threadIdx.x;
    u64* base = keys + (long long)b * MPAD + c * 2048;
    for (int t = tid; t < 2048; t += 256) sm[t] = base[t];
    __syncthreads();
    for (int k = 2; k <= 2048; k <<= 1) {
        for (int j = k >> 1; j > 0; j >>= 1) {
            for (int t = tid; t < 2048; t += 256) {
                int ixj = t ^ j;
                if (ixj > t) {
                    u64 a = sm[t], cc = sm[ixj];
                    bool up = ((t & k) == 0);
                    if (up ? (a < cc) : (a > cc)) { sm[t] = cc; sm[ixj] = a; }
                }
            }
            __syncthreads();
        }
    }
    for (int t = tid; t < 2048; t += 256) base[t] = sm[t];
}

// Half-cleaner top-2048 of two descending 2048-seqs, then bitonic cleanup.
__device__ __forceinline__ void merge_top2048(const u64* __restrict__ a,
                                              const u64* __restrict__ bseq,
                                              u64* sm, int tid) {
    for (int t = tid; t < 2048; t += 256) {
        u64 va = a[t], vb = bseq[2047 - t];
        sm[t] = va > vb ? va : vb;
    }
    __syncthreads();
    for (int j = 1024; j > 0; j >>= 1) {
        for (int t = tid; t < 2048; t += 256) {
            int ixj = t ^ j;
            if (ixj > t) {
                u64 x = sm[t], y = sm[ixj];
                if (x < y) { sm[t] = y; sm[ixj] = x; }
            }
        }
        __syncthreads();
    }
}

// Kernel 2b: round 1 — (0,1)->B0, (2,3)->B1, (4,5)->B2. grid (3, BATCH).
__global__ void merge_r1_kernel(const u64* __restrict__ keysA, u64* __restrict__ keysB) {
    __shared__ u64 sm[2048];
    const int b = blockIdx.y, c = blockIdx.x, tid = threadIdx.x;
    const u64* a = keysA + (long long)b * MPAD + c * 4096;
    merge_top2048(a, a + 2048, sm, tid);
    u64* d = keysB + (long long)b * MPAD + c * 2048;
    for (int t = tid; t < 2048; t += 256) d[t] = sm[t];
}

// Kernel 2c: round 2 — (B0,B1)->A0. grid (BATCH).
__global__ void merge_r2_kernel(const u64* __restrict__ keysB, u64* __restrict__ keysA) {
    __shared__ u64 sm[2048];
    const int b = blockIdx.x, tid = threadIdx.x;
    const u64* a = keysB + (long long)b * MPAD;
    merge_top2048(a, a + 2048, sm, tid);
    u64* d = keysA + (long long)b * MPAD;
    for (int t = tid; t < 2048; t += 256) d[t] = sm[t];
}

// Kernel 2d: round 3 — (A0,B2)->final top-2048, fused gather of corners/area.
__global__ void merge_r3_gather_kernel(const u64* __restrict__ keysA,
                                       const u64* __restrict__ keysB,
                                       const float* __restrict__ yp,
                                       float* __restrict__ sx1, float* __restrict__ sy1,
                                       float* __restrict__ sx2, float* __restrict__ sy2,
                                       float* __restrict__ sar, float* __restrict__ ssc) {
    __shared__ u64 sm[2048];
    const int b = blockIdx.x, tid = threadIdx.x;
    merge_top2048(keysA + (long long)b * MPAD, keysB + (long long)b * MPAD + 4096, sm, tid);

    for (int t = tid; t < KTOP; t += 256) {
        u64 key = sm[t];
        float s = dec_f32((u32)(key >> 32));
        u32 idx = 0xFFFFFFFFu - (u32)(key & 0xFFFFFFFFu);
        const float* r = yp + (long long)b * NROW * ROWF + (long long)idx * ROWF;
        float x = r[0], y = r[1], w = r[2], h = r[3];
        float hx = w * 0.5f, hy = h * 0.5f;
        float a1 = x - hx, b1 = y - hy, a2 = x + hx, b2 = y + hy;
        int o = b * KTOP + t;
        sx1[o] = a1; sy1[o] = b1; sx2[o] = a2; sy2[o] = b2;
        sar[o] = fmaxf(a2 - a1, 0.f) * fmaxf(b2 - b1, 0.f);
        ssc[o] = s;
    }
}

// ---------------------------------------------------------------------------
// Kernel 3: pairwise suppression bitmask, 64x64 wave tiles, upper triangle
// only (cb >= rb).  grid (132, BATCH), block 256 (4 waves).
// ---------------------------------------------------------------------------
__global__ void mask_kernel(const float* __restrict__ sx1, const float* __restrict__ sy1,
                            const float* __restrict__ sx2, const float* __restrict__ sy2,
                            const float* __restrict__ sar, u64* __restrict__ mask) {
    const int b = blockIdx.y;
    const int t = blockIdx.x * 4 + (threadIdx.x >> 6);   // 0..527
    const int lane = threadIdx.x & 63;

    // decode upper-triangle tile t -> (rb, cb), cb >= rb
    int rb = (int)((65.0f - sqrtf(4225.0f - 8.0f * (float)t)) * 0.5f);
    while (rb * (65 - rb) / 2 > t) --rb;
    while ((rb + 1) * (64 - rb) / 2 <= t) ++rb;
    const int cb = rb + t - rb * (65 - rb) / 2;

    const int oi = b * KTOP + rb * 64 + lane;
    const int oj = b * KTOP + cb * 64 + lane;
    const float rx1 = sx1[oi], ry1 = sy1[oi], rx2 = sx2[oi], ry2 = sy2[oi], ra = sar[oi];
    const float cx1 = sx1[oj], cy1 = sy1[oj], cx2 = sx2[oj], cy2 = sy2[oj], ca = sar[oj];
    const bool diag = (rb == cb);

    u64 myword = 0ULL;
    for (int ii = 0; ii < 64; ++ii) {
        float ax1 = bcast(rx1, ii), ay1 = bcast(ry1, ii);
        float ax2 = bcast(rx2, ii), ay2 = bcast(ry2, ii);
        float aa  = bcast(ra,  ii);
        float ix1 = fmaxf(ax1, cx1);
        float iy1 = fmaxf(ay1, cy1);
        float ix2 = fminf(ax2, cx2);
        float iy2 = fminf(ay2, cy2);
        float inter = fmaxf(ix2 - ix1, 0.f) * fmaxf(iy2 - iy1, 0.f);
        float uni = aa + ca - inter;
        float iou = inter / fmaxf(uni, 1e-9f);
        bool cond = (iou > IOU_THR) && (!diag || (lane > ii));
        u64 bal = __ballot(cond);
        if (lane == ii) myword = bal;
    }
    mask[(long long)(b * KTOP + rb * 64 + lane) * 32 + cb] = myword;
}

// ---------------------------------------------------------------------------
// Kernel 4: greedy reduce with LDS double-buffered mask blocks.
// Waves 1-3 prefetch block w+1's 64x32 mask words into LDS while wave 0 runs
// the serial chain (SGPR) + supp OR-reduction (LDS, 4 accumulators) on block w.
// One barrier per block.  Then all waves do the masked output write.
// grid: BATCH, block: 256.
// ---------------------------------------------------------------------------
__global__ void nms_out_kernel(const float* __restrict__ sx1, const float* __restrict__ sy1,
                               const float* __restrict__ sx2, const float* __restrict__ sy2,
                               const float* __restrict__ ssc,
                               const u64* __restrict__ mask, float* __restrict__ out) {
    __shared__ u64 db[2][64][33];   // 33 KiB, pad 33 to spread banks on column reads
    __shared__ u64 keepw[32];
    const int b = blockIdx.x;
    const int tid = threadIdx.x;
    const int lane = tid & 63;
    const int wave = tid >> 6;
    const u64* mb = mask + (long long)(b * KTOP) * 32;

    // prefetch block 0 (all threads)
    for (int idx = tid; idx < 2048; idx += 256)
        db[0][idx >> 5][idx & 31] = mb[idx];

    // init keep words: lanes 0..31 of wave 0 hold valid bits (score > thr)
    u64 myw = 0ULL;
    if (wave == 0) {
        for (int c = 0; c < 32; ++c) {
            float s = ssc[b * KTOP + c * 64 + lane];
            u64 bal = __ballot(s > SCORE_THR);
            if (lane == c) myw = bal;
        }
    }
    __syncthreads();

    for (int w = 0; w < 32; ++w) {
        if (wave > 0) {
            if (w < 31) {
                const u64* src = mb + (w + 1) * 2048;
                u64* dst = &db[(w + 1) & 1][0][0];
                for (int idx = tid - 64; idx < 2048; idx += 192)
                    dst[(idx >> 5) * 33 + (idx & 31)] = src[idx];
            }
        } else {
            const int buf = w & 1;
            // per-lane diagonal word of this block: mask[w*64+lane][w]
            u64 dia = db[buf][lane][w];

            // current keep word for this block -> SGPRs
            u64 cur_v = __shfl(myw, w);
            u64 cur = ((u64)(u32)__builtin_amdgcn_readfirstlane((u32)(cur_v >> 32)) << 32)
                    | (u64)(u32)__builtin_amdgcn_readfirstlane((u32)cur_v);

            // serial greedy within block: SALU chain, readlane broadcasts
            #pragma unroll
            for (int ii = 0; ii < 64; ++ii) {
                u64 m = ((cur >> ii) & 1ULL) ? rl64(dia, ii) : 0ULL;
                cur &= ~m;
            }

            // parallel suppression of future words from LDS, 4 accumulators.
            // lane (half=lane>>5, jb=lane&31) ORs rows ii in [half*32, half*32+32)
            const int jb = lane & 31;
            const int half = lane >> 5;
            u64 a0 = 0, a1 = 0, a2 = 0, a3 = 0;
            #pragma unroll
            for (int s8 = 0; s8 < 8; ++s8) {
                int base = half * 32 + s8 * 4;
                u64 t0 = db[buf][base + 0][jb];
                u64 t1 = db[buf][base + 1][jb];
                u64 t2 = db[buf][base + 2][jb];
                u64 t3 = db[buf][base + 3][jb];
                a0 |= ((cur >> (base + 0)) & 1ULL) ? t0 : 0ULL;
                a1 |= ((cur >> (base + 1)) & 1ULL) ? t1 : 0ULL;
                a2 |= ((cur >> (base + 2)) & 1ULL) ? t2 : 0ULL;
                a3 |= ((cur >> (base + 3)) & 1ULL) ? t3 : 0ULL;
            }
            u64 supp = (a0 | a1) | (a2 | a3);
            supp |= __shfl_xor(supp, 32);

            if (lane == w) myw = cur;
            else if (lane < 32 && lane > w) myw &= ~supp;   // jb<w words never applied
        }
        __syncthreads();
    }

    if (wave == 0 && lane < 32) keepw[lane] = myw;
    __syncthreads();

    for (int t = tid; t < KTOP; t += 256) {
        int o = b * KTOP + t;
        float f = ((keepw[t >> 6] >> (t & 63)) & 1ULL) ? 1.0f : 0.0f;
        float* op = out + (long long)o * 5;
        op[0] = sx1[o] * f;
        op[1] = sy1[o] * f;
        op[2] = sx2[o] * f;
        op[3] = sy2[o] * f;
        op[4] = ssc[o] * f;
    }
}

// ---------------------------------------------------------------------------
extern "C" void kernel_launch(void* const* d_in, const int* in_sizes, int n_in,
                              void* d_out, int out_size, void* d_ws, size_t ws_size,
                              hipStream_t stream) {
    const float* yp = (const float*)d_in[0];
    float* out = (float*)d_out;
    char* ws = (char*)d_ws;

    // Workspace layout (aliasing is safe by kernel ordering):
    //   [0, 2MiB)   keysA          (dead after merge_r3)
    //   [2, 4MiB)   keysB          (dead after merge_r3)
    //   [0, 8MiB)   mask           (written by mask_kernel, after keys die)
    //   [8MiB, +768KiB) SoA arrays (live to the end)
    const size_t KEYS_BYTES = (size_t)BATCH * MPAD * sizeof(u64);        // 2 MiB
    const size_t MASK_BYTES = (size_t)BATCH * KTOP * 32 * sizeof(u64);   // 8 MiB
    u64* keysA = (u64*)ws;
    u64* keysB = (u64*)(ws + KEYS_BYTES);
    u64* mask  = (u64*)ws;
    float* soa = (float*)(ws + MASK_BYTES);
    const int SA = BATCH * KTOP;
    float* sx1 = soa + 0 * SA;
    float* sy1 = soa + 1 * SA;
    float* sx2 = soa + 2 * SA;
    float* sy2 = soa + 3 * SA;
    float* sar = soa + 4 * SA;
    float* ssc = soa + 5 * SA;

    score_kernel<<<dim3(128, BATCH), 256, 0, stream>>>(yp, keysA);
    chunk_sort_kernel<<<dim3(6, BATCH), 256, 0, stream>>>(keysA);
    merge_r1_kernel<<<dim3(3, BATCH), 256, 0, stream>>>(keysA, keysB);
    merge_r2_kernel<<<BATCH, 256, 0, stream>>>(keysB, keysA);
    merge_r3_gather_kernel<<<BATCH, 256, 0, stream>>>(keysA, keysB, yp,
                                                      sx1, sy1, sx2, sy2, sar, ssc);
    mask_kernel<<<dim3(132, BATCH), 256, 0, stream>>>(sx1, sy1, sx2, sy2, sar, mask);
    nms_out_kernel<<<BATCH, 256, 0, stream>>>(sx1, sy1, sx2, sy2, ssc, mask, out);
}

// Round 5
// 272.615 us; speedup vs baseline: 2.1000x; 1.0773x over previous
//
#include <hip/hip_runtime.h>

// Problem constants
#define BATCH 16
#define NROW  10647
#define ROWF  85          // 4 box + 1 obj + 80 cls
#define NCLS  80
#define KTOP  2048
#define MPAD  16384       // next pow2 >= NROW
#define SCORE_THR 0.5f
#define IOU_THR   0.5f

typedef unsigned long long u64;
typedef unsigned int u32;

__device__ __forceinline__ u32 enc_f32(float f) {
    u32 u = __float_as_uint(f);
    return (u & 0x80000000u) ? ~u : (u | 0x80000000u);
}
__device__ __forceinline__ float dec_f32(u32 e) {
    u32 u = (e & 0x80000000u) ? (e & 0x7FFFFFFFu) : ~e;
    return __uint_as_float(u);
}
__device__ __forceinline__ float bcast(float v, int ii) {
    return __uint_as_float(__builtin_amdgcn_readlane(__float_as_uint(v), ii));
}
__device__ __forceinline__ u64 rl64(u64 v, int l) {
    u32 lo = __builtin_amdgcn_readlane((u32)(v & 0xFFFFFFFFull), l);
    u32 hi = __builtin_amdgcn_readlane((u32)(v >> 32), l);
    return ((u64)hi << 32) | (u64)lo;
}

// ---------------------------------------------------------------------------
// Kernel 1: scores -> sortable u64 keys.  key = enc(score)<<32 | (~idx)
// grid: (128 tiles, BATCH), block: 256.  Rows >= NROW emit key=0.
// ---------------------------------------------------------------------------
__global__ void score_kernel(const float* __restrict__ yp, u64* __restrict__ keys) {
    __shared__ float tile[128 * ROWF];   // 43520 B
    const int tileIdx = blockIdx.x;
    const int b = blockIdx.y;
    const int tid = threadIdx.x;
    const int batch_lim = NROW * ROWF;
    const int tile_base = tileIdx * 128 * ROWF;

    if (tile_base < batch_lim) {
        const float* src = yp + (long long)b * batch_lim;
        for (int e = tid; e < 128 * ROWF; e += 256) {
            float v = 0.f;
            if (tile_base + e < batch_lim) v = src[tile_base + e];
            tile[e] = v;
        }
    }
    __syncthreads();

    if (tid < 128) {
        int gr = tileIdx * 128 + tid;          // < MPAD always
        u64 key = 0ULL;
        if (gr < NROW) {
            const float* r = &tile[tid * ROWF];
            float obj = r[4];
            float m = r[5];
            #pragma unroll
            for (int c = 1; c < NCLS; ++c) m = fmaxf(m, r[5 + c]);
            float s = obj * m;
            key = ((u64)enc_f32(s) << 32) | (u64)(0xFFFFFFFFu - (u32)gr);
        }
        keys[(long long)b * MPAD + gr] = key;
    }
}

// ---------------------------------------------------------------------------
// Kernel 2a: sort each 2048-chunk descending (chunks 0..5 cover all real rows;
// chunks 6,7 are all-zero keys and are skipped). grid (6, BATCH), block 256.
// ---------------------------------------------------------------------------
__global__ void chunk_sort_kernel(u64* __restrict__ keys) {
    __shared__ u64 sm[2048];   // 16 KiB
    const int b = blockIdx.y, c = blockIdx.x, tid = threadIdx.x;
    u64* base = keys + (long long)b * MPAD + c * 2048;
    for (int t = tid; t < 2048; t += 256) sm[t] = base[t];
    __syncthreads();
    for (int k = 2; k <= 2048; k <<= 1) {
        for (int j = k >> 1; j > 0; j >>= 1) {
            for (int t = tid; t < 2048; t += 256) {
                int ixj = t ^ j;
                if (ixj > t) {
                    u64 a = sm[t], cc = sm[ixj];
                    bool up = ((t & k) == 0);
                    if (up ? (a < cc) : (a > cc)) { sm[t] = cc; sm[ixj] = a; }
                }
            }
            __syncthreads();
        }
    }
    for (int t = tid; t < 2048; t += 256) base[t] = sm[t];
}

// Half-cleaner top-2048 of two descending 2048-seqs, then bitonic cleanup.
__device__ __forceinline__ void merge_top2048(const u64* __restrict__ a,
                                              const u64* __restrict__ bseq,
                                              u64* sm, int tid) {
    for (int t = tid; t < 2048; t += 256) {
        u64 va = a[t], vb = bseq[2047 - t];
        sm[t] = va > vb ? va : vb;
    }
    __syncthreads();
    for (int j = 1024; j > 0; j >>= 1) {
        for (int t = tid; t < 2048; t += 256) {
            int ixj = t ^ j;
            if (ixj > t) {
                u64 x = sm[t], y = sm[ixj];
                if (x < y) { sm[t] = y; sm[ixj] = x; }
            }
        }
        __syncthreads();
    }
}

// Kernel 2b: round 1 — (0,1)->B0, (2,3)->B1, (4,5)->B2. grid (3, BATCH).
__global__ void merge_r1_kernel(const u64* __restrict__ keysA, u64* __restrict__ keysB) {
    __shared__ u64 sm[2048];
    const int b = blockIdx.y, c = blockIdx.x, tid = threadIdx.x;
    const u64* a = keysA + (long long)b * MPAD + c * 4096;
    merge_top2048(a, a + 2048, sm, tid);
    u64* d = keysB + (long long)b * MPAD + c * 2048;
    for (int t = tid; t < 2048; t += 256) d[t] = sm[t];
}

// Kernel 2c: round 2 — (B0,B1)->A0. grid (BATCH).
__global__ void merge_r2_kernel(const u64* __restrict__ keysB, u64* __restrict__ keysA) {
    __shared__ u64 sm[2048];
    const int b = blockIdx.x, tid = threadIdx.x;
    const u64* a = keysB + (long long)b * MPAD;
    merge_top2048(a, a + 2048, sm, tid);
    u64* d = keysA + (long long)b * MPAD;
    for (int t = tid; t < 2048; t += 256) d[t] = sm[t];
}

// Kernel 2d: round 3 — (A0,B2)->final top-2048, fused gather of corners/area.
__global__ void merge_r3_gather_kernel(const u64* __restrict__ keysA,
                                       const u64* __restrict__ keysB,
                                       const float* __restrict__ yp,
                                       float* __restrict__ sx1, float* __restrict__ sy1,
                                       float* __restrict__ sx2, float* __restrict__ sy2,
                                       float* __restrict__ sar, float* __restrict__ ssc) {
    __shared__ u64 sm[2048];
    const int b = blockIdx.x, tid = threadIdx.x;
    merge_top2048(keysA + (long long)b * MPAD, keysB + (long long)b * MPAD + 4096, sm, tid);

    for (int t = tid; t < KTOP; t += 256) {
        u64 key = sm[t];
        float s = dec_f32((u32)(key >> 32));
        u32 idx = 0xFFFFFFFFu - (u32)(key & 0xFFFFFFFFu);
        const float* r = yp + (long long)b * NROW * ROWF + (long long)idx * ROWF;
        float x = r[0], y = r[1], w = r[2], h = r[3];
        float hx = w * 0.5f, hy = h * 0.5f;
        float a1 = x - hx, b1 = y - hy, a2 = x + hx, b2 = y + hy;
        int o = b * KTOP + t;
        sx1[o] = a1; sy1[o] = b1; sx2[o] = a2; sy2[o] = b2;
        sar[o] = fmaxf(a2 - a1, 0.f) * fmaxf(b2 - b1, 0.f);
        ssc[o] = s;
    }
}

// ---------------------------------------------------------------------------
// Kernel 3: pairwise suppression bitmask, 64x64 wave tiles, upper triangle
// only (cb >= rb).  grid (132, BATCH), block 256 (4 waves).
// ---------------------------------------------------------------------------
__global__ void mask_kernel(const float* __restrict__ sx1, const float* __restrict__ sy1,
                            const float* __restrict__ sx2, const float* __restrict__ sy2,
                            const float* __restrict__ sar, u64* __restrict__ mask) {
    const int b = blockIdx.y;
    const int t = blockIdx.x * 4 + (threadIdx.x >> 6);   // 0..527
    const int lane = threadIdx.x & 63;

    // decode upper-triangle tile t -> (rb, cb), cb >= rb
    int rb = (int)((65.0f - sqrtf(4225.0f - 8.0f * (float)t)) * 0.5f);
    while (rb * (65 - rb) / 2 > t) --rb;
    while ((rb + 1) * (64 - rb) / 2 <= t) ++rb;
    const int cb = rb + t - rb * (65 - rb) / 2;

    const int oi = b * KTOP + rb * 64 + lane;
    const int oj = b * KTOP + cb * 64 + lane;
    const float rx1 = sx1[oi], ry1 = sy1[oi], rx2 = sx2[oi], ry2 = sy2[oi], ra = sar[oi];
    const float cx1 = sx1[oj], cy1 = sy1[oj], cx2 = sx2[oj], cy2 = sy2[oj], ca = sar[oj];
    const bool diag = (rb == cb);

    u64 myword = 0ULL;
    for (int ii = 0; ii < 64; ++ii) {
        float ax1 = bcast(rx1, ii), ay1 = bcast(ry1, ii);
        float ax2 = bcast(rx2, ii), ay2 = bcast(ry2, ii);
        float aa  = bcast(ra,  ii);
        float ix1 = fmaxf(ax1, cx1);
        float iy1 = fmaxf(ay1, cy1);
        float ix2 = fminf(ax2, cx2);
        float iy2 = fminf(ay2, cy2);
        float inter = fmaxf(ix2 - ix1, 0.f) * fmaxf(iy2 - iy1, 0.f);
        float uni = aa + ca - inter;
        float iou = inter / fmaxf(uni, 1e-9f);
        bool cond = (iou > IOU_THR) && (!diag || (lane > ii));
        u64 bal = __ballot(cond);
        if (lane == ii) myword = bal;
    }
    mask[(long long)(b * KTOP + rb * 64 + lane) * 32 + cb] = myword;
}

// ---------------------------------------------------------------------------
// Kernel 4: greedy reduce with LDS double-buffered mask blocks.
// Waves 1-3 prefetch block w+1 via REGISTER-STAGED loads (all global loads
// issued before any LDS write -> latency paid once, overlapped with wave 0's
// chain) while wave 0 runs the serial chain (SGPR) + supp OR-reduction (LDS).
// grid: BATCH, block: 256.
// ---------------------------------------------------------------------------
__global__ void nms_out_kernel(const float* __restrict__ sx1, const float* __restrict__ sy1,
                               const float* __restrict__ sx2, const float* __restrict__ sy2,
                               const float* __restrict__ ssc,
                               const u64* __restrict__ mask, float* __restrict__ out) {
    __shared__ u64 db[2][64][33];   // 33 KiB, pad 33 to spread banks on column reads
    __shared__ u64 keepw[32];
    const int b = blockIdx.x;
    const int tid = threadIdx.x;
    const int lane = tid & 63;
    const int wave = tid >> 6;
    const u64* mb = mask + (long long)(b * KTOP) * 32;

    // prefetch block 0 (all threads), register-staged
    {
        u64 r[8];
        #pragma unroll
        for (int k = 0; k < 8; ++k) r[k] = mb[tid + k * 256];
        #pragma unroll
        for (int k = 0; k < 8; ++k) {
            int idx = tid + k * 256;
            db[0][idx >> 5][idx & 31] = r[k];
        }
    }

    // init keep words: lanes 0..31 of wave 0 hold valid bits (score > thr)
    u64 myw = 0ULL;
    if (wave == 0) {
        for (int c = 0; c < 32; ++c) {
            float s = ssc[b * KTOP + c * 64 + lane];
            u64 bal = __ballot(s > SCORE_THR);
            if (lane == c) myw = bal;
        }
    }
    __syncthreads();

    for (int w = 0; w < 32; ++w) {
        if (wave > 0) {
            if (w < 31) {
                const u64* src = mb + (w + 1) * 2048;
                u64* dst = &db[(w + 1) & 1][0][0];
                const int pid = tid - 64;                 // 0..191
                u64 r[11];
                #pragma unroll
                for (int k = 0; k < 11; ++k) {
                    int idx = pid + k * 192;
                    r[k] = (idx < 2048) ? src[idx] : 0ULL;   // all loads issue first
                }
                #pragma unroll
                for (int k = 0; k < 11; ++k) {
                    int idx = pid + k * 192;
                    if (idx < 2048) dst[(idx >> 5) * 33 + (idx & 31)] = r[k];
                }
            }
        } else {
            const int buf = w & 1;
            // per-lane diagonal word of this block: mask[w*64+lane][w]
            u64 dia = db[buf][lane][w];

            // current keep word for this block -> SGPRs
            u64 cur_v = __shfl(myw, w);
            u64 cur = ((u64)(u32)__builtin_amdgcn_readfirstlane((u32)(cur_v >> 32)) << 32)
                    | (u64)(u32)__builtin_amdgcn_readfirstlane((u32)cur_v);

            // serial greedy within block: SALU chain, readlane broadcasts
            #pragma unroll
            for (int ii = 0; ii < 64; ++ii) {
                u64 m = ((cur >> ii) & 1ULL) ? rl64(dia, ii) : 0ULL;
                cur &= ~m;
            }

            // parallel suppression of future words from LDS, 4 accumulators.
            // lane (half=lane>>5, jb=lane&31) ORs rows ii in [half*32, half*32+32)
            const int jb = lane & 31;
            const int half = lane >> 5;
            u64 a0 = 0, a1 = 0, a2 = 0, a3 = 0;
            #pragma unroll
            for (int s8 = 0; s8 < 8; ++s8) {
                int base = half * 32 + s8 * 4;
                u64 t0 = db[buf][base + 0][jb];
                u64 t1 = db[buf][base + 1][jb];
                u64 t2 = db[buf][base + 2][jb];
                u64 t3 = db[buf][base + 3][jb];
                a0 |= ((cur >> (base + 0)) & 1ULL) ? t0 : 0ULL;
                a1 |= ((cur >> (base + 1)) & 1ULL) ? t1 : 0ULL;
                a2 |= ((cur >> (base + 2)) & 1ULL) ? t2 : 0ULL;
                a3 |= ((cur >> (base + 3)) & 1ULL) ? t3 : 0ULL;
            }
            u64 supp = (a0 | a1) | (a2 | a3);
            supp |= __shfl_xor(supp, 32);

            if (lane == w) myw = cur;
            else if (lane < 32 && lane > w) myw &= ~supp;   // jb<w words never applied
        }
        __syncthreads();
    }

    if (wave == 0 && lane < 32) keepw[lane] = myw;
    __syncthreads();

    for (int t = tid; t < KTOP; t += 256) {
        int o = b * KTOP + t;
        float f = ((keepw[t >> 6] >> (t & 63)) & 1ULL) ? 1.0f : 0.0f;
        float* op = out + (long long)o * 5;
        op[0] = sx1[o] * f;
        op[1] = sy1[o] * f;
        op[2] = sx2[o] * f;
        op[3] = sy2[o] * f;
        op[4] = ssc[o] * f;
    }
}

// ---------------------------------------------------------------------------
extern "C" void kernel_launch(void* const* d_in, const int* in_sizes, int n_in,
                              void* d_out, int out_size, void* d_ws, size_t ws_size,
                              hipStream_t stream) {
    const float* yp = (const float*)d_in[0];
    float* out = (float*)d_out;
    char* ws = (char*)d_ws;

    // Workspace layout (aliasing is safe by kernel ordering):
    //   [0, 2MiB)   keysA          (dead after merge_r3)
    //   [2, 4MiB)   keysB          (dead after merge_r3)
    //   [0, 8MiB)   mask           (written by mask_kernel, after keys die)
    //   [8MiB, +768KiB) SoA arrays (live to the end)
    const size_t KEYS_BYTES = (size_t)BATCH * MPAD * sizeof(u64);        // 2 MiB
    const size_t MASK_BYTES = (size_t)BATCH * KTOP * 32 * sizeof(u64);   // 8 MiB
    u64* keysA = (u64*)ws;
    u64* keysB = (u64*)(ws + KEYS_BYTES);
    u64* mask  = (u64*)ws;
    float* soa = (float*)(ws + MASK_BYTES);
    const int SA = BATCH * KTOP;
    float* sx1 = soa + 0 * SA;
    float* sy1 = soa + 1 * SA;
    float* sx2 = soa + 2 * SA;
    float* sy2 = soa + 3 * SA;
    float* sar = soa + 4 * SA;
    float* ssc = soa + 5 * SA;

    score_kernel<<<dim3(128, BATCH), 256, 0, stream>>>(yp, keysA);
    chunk_sort_kernel<<<dim3(6, BATCH), 256, 0, stream>>>(keysA);
    merge_r1_kernel<<<dim3(3, BATCH), 256, 0, stream>>>(keysA, keysB);
    merge_r2_kernel<<<BATCH, 256, 0, stream>>>(keysB, keysA);
    merge_r3_gather_kernel<<<BATCH, 256, 0, stream>>>(keysA, keysB, yp,
                                                      sx1, sy1, sx2, sy2, sar, ssc);
    mask_kernel<<<dim3(132, BATCH), 256, 0, stream>>>(sx1, sy1, sx2, sy2, sar, mask);
    nms_out_kernel<<<BATCH, 256, 0, stream>>>(sx1, sy1, sx2, sy2, ssc, mask, out);
}

// Round 6
// 198.909 us; speedup vs baseline: 2.8781x; 1.3705x over previous
//
#include <hip/hip_runtime.h>

// Problem constants
#define BATCH 16
#define NROW  10647
#define ROWF  85          // 4 box + 1 obj + 80 cls
#define NCLS  80
#define KTOP  2048
#define MPAD  16384       // next pow2 >= NROW
#define SCORE_THR 0.5f
#define IOU_THR   0.5f

typedef unsigned long long u64;
typedef unsigned int u32;

__device__ __forceinline__ u32 enc_f32(float f) {
    u32 u = __float_as_uint(f);
    return (u & 0x80000000u) ? ~u : (u | 0x80000000u);
}
__device__ __forceinline__ float dec_f32(u32 e) {
    u32 u = (e & 0x80000000u) ? (e & 0x7FFFFFFFu) : ~e;
    return __uint_as_float(u);
}
__device__ __forceinline__ float bcast(float v, int ii) {
    return __uint_as_float(__builtin_amdgcn_readlane(__float_as_uint(v), ii));
}
__device__ __forceinline__ u64 rl64(u64 v, int l) {
    u32 lo = __builtin_amdgcn_readlane((u32)(v & 0xFFFFFFFFull), l);
    u32 hi = __builtin_amdgcn_readlane((u32)(v >> 32), l);
    return ((u64)hi << 32) | (u64)lo;
}

// ===========================================================================
// Register-resident bitonic sort: 256 threads x 8 elements, e = tid*8 + r.
// j<=4: in-register (compile-time J).  8<=j<=256: intra-wave shfl_xor
// (d = j/8 <= 32).  j in {512,1024}: LDS round-trip at conflict-free layout
// sm[r*256+tid].  Directions: keep max at bit-clear position iff (e&k)==0
// (descending overall at k=2048) — identical network to the validated LDS
// version, so output is bit-exact.
// ===========================================================================
template<int J>
__device__ __forceinline__ void reg_pass(u64 v[8], int tid, int k) {
    #pragma unroll
    for (int r = 0; r < 8; ++r) {
        if (!(r & J)) {
            bool desc = (((tid * 8 + r) & k) == 0);
            u64 a = v[r], b = v[r | J];
            u64 mx = a > b ? a : b, mn = a > b ? b : a;
            v[r]     = desc ? mx : mn;
            v[r | J] = desc ? mn : mx;
        }
    }
}

__device__ __forceinline__ void shfl_pass(u64 v[8], int tid, int k, int d) {
    const bool upper = (tid & d) == 0;
    const bool desc = (((tid * 8) & k) == 0);
    const bool keepmax = (desc == upper);
    #pragma unroll
    for (int r = 0; r < 8; ++r) {
        u64 pv = __shfl_xor(v[r], d);
        u64 mx = v[r] > pv ? v[r] : pv, mn = v[r] > pv ? pv : v[r];
        v[r] = keepmax ? mx : mn;
    }
}

__device__ __forceinline__ void lds_pass(u64 v[8], int tid, u64* sm, int k, int d) {
    __syncthreads();
    #pragma unroll
    for (int r = 0; r < 8; ++r) sm[r * 256 + tid] = v[r];
    __syncthreads();
    const bool upper = (tid & d) == 0;
    const bool desc = (((tid * 8) & k) == 0);
    const bool keepmax = (desc == upper);
    const int pt = tid ^ d;
    #pragma unroll
    for (int r = 0; r < 8; ++r) {
        u64 pv = sm[r * 256 + pt];
        u64 mx = v[r] > pv ? v[r] : pv, mn = v[r] > pv ? pv : v[r];
        v[r] = keepmax ? mx : mn;
    }
}

__device__ __forceinline__ void sort2048_desc(u64 v[8], int tid, u64* sm) {
    reg_pass<1>(v, tid, 2);
    reg_pass<2>(v, tid, 4); reg_pass<1>(v, tid, 4);
    for (int k = 8; k <= 2048; k <<= 1) {
        for (int j = k >> 1; j >= 8; j >>= 1) {
            int d = j >> 3;
            if (d <= 32) shfl_pass(v, tid, k, d);
            else         lds_pass(v, tid, sm, k, d);
        }
        reg_pass<4>(v, tid, k); reg_pass<2>(v, tid, k); reg_pass<1>(v, tid, k);
    }
}

// Bitonic cleanup (all-descending), j = 1024..1 — for the top-2048 merge.
__device__ __forceinline__ void cleanup2048_desc(u64 v[8], int tid, u64* sm) {
    lds_pass(v, tid, sm, 4096, 128);   // j = 1024
    lds_pass(v, tid, sm, 4096, 64);    // j = 512
    for (int d = 32; d >= 1; d >>= 1) shfl_pass(v, tid, 4096, d);
    reg_pass<4>(v, tid, 4096); reg_pass<2>(v, tid, 4096); reg_pass<1>(v, tid, 4096);
}

// ---------------------------------------------------------------------------
// Kernel 1: scores -> sortable u64 keys.  key = enc(score)<<32 | (~idx)
// grid: (128 tiles, BATCH), block: 256.  Rows >= NROW emit key=0.
// ---------------------------------------------------------------------------
__global__ void score_kernel(const float* __restrict__ yp, u64* __restrict__ keys) {
    __shared__ float tile[128 * ROWF];   // 43520 B
    const int tileIdx = blockIdx.x;
    const int b = blockIdx.y;
    const int tid = threadIdx.x;
    const int batch_lim = NROW * ROWF;
    const int tile_base = tileIdx * 128 * ROWF;

    if (tile_base < batch_lim) {
        const float* src = yp + (long long)b * batch_lim;
        for (int e = tid; e < 128 * ROWF; e += 256) {
            float v = 0.f;
            if (tile_base + e < batch_lim) v = src[tile_base + e];
            tile[e] = v;
        }
    }
    __syncthreads();

    if (tid < 128) {
        int gr = tileIdx * 128 + tid;          // < MPAD always
        u64 key = 0ULL;
        if (gr < NROW) {
            const float* r = &tile[tid * ROWF];
            float obj = r[4];
            float m = r[5];
            #pragma unroll
            for (int c = 1; c < NCLS; ++c) m = fmaxf(m, r[5 + c]);
            float s = obj * m;
            key = ((u64)enc_f32(s) << 32) | (u64)(0xFFFFFFFFu - (u32)gr);
        }
        keys[(long long)b * MPAD + gr] = key;
    }
}

// ---------------------------------------------------------------------------
// Kernel 2a: sort each 2048-chunk descending (register bitonic).
// grid (6, BATCH), block 256.
// ---------------------------------------------------------------------------
__global__ void chunk_sort_kernel(u64* __restrict__ keys) {
    __shared__ u64 sm[2048];   // 16 KiB, cross-wave exchange buffer
    const int b = blockIdx.y, c = blockIdx.x, tid = threadIdx.x;
    u64* base = keys + (long long)b * MPAD + c * 2048;
    u64 v[8];
    #pragma unroll
    for (int r = 0; r < 8; ++r) v[r] = base[tid * 8 + r];
    sort2048_desc(v, tid, sm);
    #pragma unroll
    for (int r = 0; r < 8; ++r) base[tid * 8 + r] = v[r];
}

// Kernel 2b: round 1 — (0,1)->B0, (2,3)->B1, (4,5)->B2. grid (3, BATCH).
__global__ void merge_r1_kernel(const u64* __restrict__ keysA, u64* __restrict__ keysB) {
    __shared__ u64 sm[2048];
    const int b = blockIdx.y, c = blockIdx.x, tid = threadIdx.x;
    const u64* a = keysA + (long long)b * MPAD + c * 4096;
    u64 v[8];
    #pragma unroll
    for (int r = 0; r < 8; ++r) {
        int e = tid * 8 + r;
        u64 va = a[e], vb = a[4095 - e];
        v[r] = va > vb ? va : vb;
    }
    cleanup2048_desc(v, tid, sm);
    u64* d = keysB + (long long)b * MPAD + c * 2048;
    #pragma unroll
    for (int r = 0; r < 8; ++r) d[tid * 8 + r] = v[r];
}

// Kernel 2c: round 2 — (B0,B1)->A0. grid (BATCH).
__global__ void merge_r2_kernel(const u64* __restrict__ keysB, u64* __restrict__ keysA) {
    __shared__ u64 sm[2048];
    const int b = blockIdx.x, tid = threadIdx.x;
    const u64* a = keysB + (long long)b * MPAD;
    u64 v[8];
    #pragma unroll
    for (int r = 0; r < 8; ++r) {
        int e = tid * 8 + r;
        u64 va = a[e], vb = a[4095 - e];
        v[r] = va > vb ? va : vb;
    }
    cleanup2048_desc(v, tid, sm);
    u64* d = keysA + (long long)b * MPAD;
    #pragma unroll
    for (int r = 0; r < 8; ++r) d[tid * 8 + r] = v[r];
}

// Kernel 2d: round 3 — (A0,B2)->final top-2048, fused gather of corners/area.
__global__ void merge_r3_gather_kernel(const u64* __restrict__ keysA,
                                       const u64* __restrict__ keysB,
                                       const float* __restrict__ yp,
                                       float* __restrict__ sx1, float* __restrict__ sy1,
                                       float* __restrict__ sx2, float* __restrict__ sy2,
                                       float* __restrict__ sar, float* __restrict__ ssc) {
    __shared__ u64 sm[2048];
    const int b = blockIdx.x, tid = threadIdx.x;
    const u64* a = keysA + (long long)b * MPAD;
    const u64* bb = keysB + (long long)b * MPAD + 4096;
    u64 v[8];
    #pragma unroll
    for (int r = 0; r < 8; ++r) {
        int e = tid * 8 + r;
        u64 va = a[e], vb = bb[2047 - e];
        v[r] = va > vb ? va : vb;
    }
    cleanup2048_desc(v, tid, sm);

    #pragma unroll
    for (int r = 0; r < 8; ++r) {
        u64 key = v[r];
        float s = dec_f32((u32)(key >> 32));
        u32 idx = 0xFFFFFFFFu - (u32)(key & 0xFFFFFFFFu);
        const float* rp = yp + (long long)b * NROW * ROWF + (long long)idx * ROWF;
        float x = rp[0], y = rp[1], w = rp[2], h = rp[3];
        float hx = w * 0.5f, hy = h * 0.5f;
        float a1 = x - hx, b1 = y - hy, a2 = x + hx, b2 = y + hy;
        int o = b * KTOP + tid * 8 + r;
        sx1[o] = a1; sy1[o] = b1; sx2[o] = a2; sy2[o] = b2;
        sar[o] = fmaxf(a2 - a1, 0.f) * fmaxf(b2 - b1, 0.f);
        ssc[o] = s;
    }
}

// ---------------------------------------------------------------------------
// Kernel 3: pairwise suppression bitmask, 64x64 wave tiles, upper triangle
// only (cb >= rb).  grid (132, BATCH), block 256 (4 waves).
// ---------------------------------------------------------------------------
__global__ void mask_kernel(const float* __restrict__ sx1, const float* __restrict__ sy1,
                            const float* __restrict__ sx2, const float* __restrict__ sy2,
                            const float* __restrict__ sar, u64* __restrict__ mask) {
    const int b = blockIdx.y;
    const int t = blockIdx.x * 4 + (threadIdx.x >> 6);   // 0..527
    const int lane = threadIdx.x & 63;

    // decode upper-triangle tile t -> (rb, cb), cb >= rb
    int rb = (int)((65.0f - sqrtf(4225.0f - 8.0f * (float)t)) * 0.5f);
    while (rb * (65 - rb) / 2 > t) --rb;
    while ((rb + 1) * (64 - rb) / 2 <= t) ++rb;
    const int cb = rb + t - rb * (65 - rb) / 2;

    const int oi = b * KTOP + rb * 64 + lane;
    const int oj = b * KTOP + cb * 64 + lane;
    const float rx1 = sx1[oi], ry1 = sy1[oi], rx2 = sx2[oi], ry2 = sy2[oi], ra = sar[oi];
    const float cx1 = sx1[oj], cy1 = sy1[oj], cx2 = sx2[oj], cy2 = sy2[oj], ca = sar[oj];
    const bool diag = (rb == cb);

    u64 myword = 0ULL;
    for (int ii = 0; ii < 64; ++ii) {
        float ax1 = bcast(rx1, ii), ay1 = bcast(ry1, ii);
        float ax2 = bcast(rx2, ii), ay2 = bcast(ry2, ii);
        float aa  = bcast(ra,  ii);
        float ix1 = fmaxf(ax1, cx1);
        float iy1 = fmaxf(ay1, cy1);
        float ix2 = fminf(ax2, cx2);
        float iy2 = fminf(ay2, cy2);
        float inter = fmaxf(ix2 - ix1, 0.f) * fmaxf(iy2 - iy1, 0.f);
        float uni = aa + ca - inter;
        float iou = inter / fmaxf(uni, 1e-9f);
        bool cond = (iou > IOU_THR) && (!diag || (lane > ii));
        u64 bal = __ballot(cond);
        if (lane == ii) myword = bal;
    }
    mask[(long long)(b * KTOP + rb * 64 + lane) * 32 + cb] = myword;
}

// ---------------------------------------------------------------------------
// Kernel 4: greedy reduce with LDS double-buffered mask blocks.
// Waves 1-3 prefetch block w+1 via register-staged loads; wave 0 runs the
// serial chain (SGPR) + supp OR-reduction (LDS).  grid: BATCH, block: 256.
// ---------------------------------------------------------------------------
__global__ void nms_out_kernel(const float* __restrict__ sx1, const float* __restrict__ sy1,
                               const float* __restrict__ sx2, const float* __restrict__ sy2,
                               const float* __restrict__ ssc,
                               const u64* __restrict__ mask, float* __restrict__ out) {
    __shared__ u64 db[2][64][33];   // 33 KiB, pad 33 to spread banks on column reads
    __shared__ u64 keepw[32];
    const int b = blockIdx.x;
    const int tid = threadIdx.x;
    const int lane = tid & 63;
    const int wave = tid >> 6;
    const u64* mb = mask + (long long)(b * KTOP) * 32;

    // prefetch block 0 (all threads), register-staged
    {
        u64 r[8];
        #pragma unroll
        for (int k = 0; k < 8; ++k) r[k] = mb[tid + k * 256];
        #pragma unroll
        for (int k = 0; k < 8; ++k) {
            int idx = tid + k * 256;
            db[0][idx >> 5][idx & 31] = r[k];
        }
    }

    // init keep words: lanes 0..31 of wave 0 hold valid bits (score > thr)
    u64 myw = 0ULL;
    if (wave == 0) {
        for (int c = 0; c < 32; ++c) {
            float s = ssc[b * KTOP + c * 64 + lane];
            u64 bal = __ballot(s > SCORE_THR);
            if (lane == c) myw = bal;
        }
    }
    __syncthreads();

    for (int w = 0; w < 32; ++w) {
        if (wave > 0) {
            if (w < 31) {
                const u64* src = mb + (w + 1) * 2048;
                u64* dst = &db[(w + 1) & 1][0][0];
                const int pid = tid - 64;                 // 0..191
                u64 r[11];
                #pragma unroll
                for (int k = 0; k < 11; ++k) {
                    int idx = pid + k * 192;
                    r[k] = (idx < 2048) ? src[idx] : 0ULL;   // all loads issue first
                }
                #pragma unroll
                for (int k = 0; k < 11; ++k) {
                    int idx = pid + k * 192;
                    if (idx < 2048) dst[(idx >> 5) * 33 + (idx & 31)] = r[k];
                }
            }
        } else {
            const int buf = w & 1;
            // per-lane diagonal word of this block: mask[w*64+lane][w]
            u64 dia = db[buf][lane][w];

            // current keep word for this block -> SGPRs
            u64 cur_v = __shfl(myw, w);
            u64 cur = ((u64)(u32)__builtin_amdgcn_readfirstlane((u32)(cur_v >> 32)) << 32)
                    | (u64)(u32)__builtin_amdgcn_readfirstlane((u32)cur_v);

            // serial greedy within block: SALU chain, readlane broadcasts
            #pragma unroll
            for (int ii = 0; ii < 64; ++ii) {
                u64 m = ((cur >> ii) & 1ULL) ? rl64(dia, ii) : 0ULL;
                cur &= ~m;
            }

            // parallel suppression of future words from LDS, 4 accumulators.
            const int jb = lane & 31;
            const int half = lane >> 5;
            u64 a0 = 0, a1 = 0, a2 = 0, a3 = 0;
            #pragma unroll
            for (int s8 = 0; s8 < 8; ++s8) {
                int base = half * 32 + s8 * 4;
                u64 t0 = db[buf][base + 0][jb];
                u64 t1 = db[buf][base + 1][jb];
                u64 t2 = db[buf][base + 2][jb];
                u64 t3 = db[buf][base + 3][jb];
                a0 |= ((cur >> (base + 0)) & 1ULL) ? t0 : 0ULL;
                a1 |= ((cur >> (base + 1)) & 1ULL) ? t1 : 0ULL;
                a2 |= ((cur >> (base + 2)) & 1ULL) ? t2 : 0ULL;
                a3 |= ((cur >> (base + 3)) & 1ULL) ? t3 : 0ULL;
            }
            u64 supp = (a0 | a1) | (a2 | a3);
            supp |= __shfl_xor(supp, 32);

            if (lane == w) myw = cur;
            else if (lane < 32 && lane > w) myw &= ~supp;   // jb<w words never applied
        }
        __syncthreads();
    }

    if (wave == 0 && lane < 32) keepw[lane] = myw;
    __syncthreads();

    for (int t = tid; t < KTOP; t += 256) {
        int o = b * KTOP + t;
        float f = ((keepw[t >> 6] >> (t & 63)) & 1ULL) ? 1.0f : 0.0f;
        float* op = out + (long long)o * 5;
        op[0] = sx1[o] * f;
        op[1] = sy1[o] * f;
        op[2] = sx2[o] * f;
        op[3] = sy2[o] * f;
        op[4] = ssc[o] * f;
    }
}

// ---------------------------------------------------------------------------
extern "C" void kernel_launch(void* const* d_in, const int* in_sizes, int n_in,
                              void* d_out, int out_size, void* d_ws, size_t ws_size,
                              hipStream_t stream) {
    const float* yp = (const float*)d_in[0];
    float* out = (float*)d_out;
    char* ws = (char*)d_ws;

    // Workspace layout (aliasing is safe by kernel ordering):
    //   [0, 2MiB)   keysA          (dead after merge_r3)
    //   [2, 4MiB)   keysB          (dead after merge_r3)
    //   [0, 8MiB)   mask           (written by mask_kernel, after keys die)
    //   [8MiB, +768KiB) SoA arrays (live to the end)
    const size_t KEYS_BYTES = (size_t)BATCH * MPAD * sizeof(u64);        // 2 MiB
    const size_t MASK_BYTES = (size_t)BATCH * KTOP * 32 * sizeof(u64);   // 8 MiB
    u64* keysA = (u64*)ws;
    u64* keysB = (u64*)(ws + KEYS_BYTES);
    u64* mask  = (u64*)ws;
    float* soa = (float*)(ws + MASK_BYTES);
    const int SA = BATCH * KTOP;
    float* sx1 = soa + 0 * SA;
    float* sy1 = soa + 1 * SA;
    float* sx2 = soa + 2 * SA;
    float* sy2 = soa + 3 * SA;
    float* sar = soa + 4 * SA;
    float* ssc = soa + 5 * SA;

    score_kernel<<<dim3(128, BATCH), 256, 0, stream>>>(yp, keysA);
    chunk_sort_kernel<<<dim3(6, BATCH), 256, 0, stream>>>(keysA);
    merge_r1_kernel<<<dim3(3, BATCH), 256, 0, stream>>>(keysA, keysB);
    merge_r2_kernel<<<BATCH, 256, 0, stream>>>(keysB, keysA);
    merge_r3_gather_kernel<<<BATCH, 256, 0, stream>>>(keysA, keysB, yp,
                                                      sx1, sy1, sx2, sy2, sar, ssc);
    mask_kernel<<<dim3(132, BATCH), 256, 0, stream>>>(sx1, sy1, sx2, sy2, sar, mask);
    nms_out_kernel<<<BATCH, 256, 0, stream>>>(sx1, sy1, sx2, sy2, ssc, mask, out);
}